// Round 18
// baseline (509.371 us; speedup 1.0000x reference)
//
#include <hip/hip_runtime.h>
#include <hip/hip_bf16.h>
#include <stdint.h>

using bf16_t = __bf16;
using bf16x8 = __attribute__((ext_vector_type(8))) __bf16;
using bf16x4 = __attribute__((ext_vector_type(4))) __bf16;
using f32x4  = __attribute__((ext_vector_type(4))) float;

#define D_MODEL 3072
#define N_HEADS 24
#define HEAD_DIM 128
#define Q_PROJ 1536
#define KV_PROJ 2048
#define ROPE_DIM 64
#define S_LEN 2048
#define NTOK 4096            // B*S
#define KVDN 2112            // KV_PROJ + ROPE_DIM
#define KVUN 4608            // D_MODEL + N_HEADS*ROPE_DIM

// ---- async global->LDS (16B per lane, wave-uniform LDS base) ----
__device__ __forceinline__ void async_ld16(const void* g, void* l) {
    __builtin_amdgcn_global_load_lds(
        (__attribute__((address_space(1))) uint32_t*)(uintptr_t)g,
        (__attribute__((address_space(3))) uint32_t*)(uint32_t)(uintptr_t)l,
        16, 0, 0);
}

#define BARRIER() __builtin_amdgcn_s_barrier()
#define WAITVN(n) asm volatile("s_waitcnt vmcnt(" #n ")" ::: "memory")

// ==  fused pre-pass: RMSNorm (blocks 0..4095) + weight prep (blocks 4096..38079)  ==
__global__ __launch_bounds__(256) void fused_pre(
    const float* __restrict__ x, const float* __restrict__ sc, bf16_t* __restrict__ xn,
    const float* __restrict__ w_dq, const float* __restrict__ w_uq,
    const float* __restrict__ w_dkv, const float* __restrict__ w_ukv,
    const float* __restrict__ w_o,
    bf16_t* __restrict__ wcat, bf16_t* __restrict__ wuqt,
    bf16_t* __restrict__ wukvt, bf16_t* __restrict__ wob)
{
    __shared__ float tile[32][33];
    const int tid = threadIdx.x;
    if (blockIdx.x < NTOK) {
        const int tok = blockIdx.x;
        const float4* xr = (const float4*)(x + (size_t)tok * D_MODEL);
        float4 a = xr[tid], b = xr[tid + 256], c = xr[tid + 512];
        float ss = a.x*a.x + a.y*a.y + a.z*a.z + a.w*a.w
                 + b.x*b.x + b.y*b.y + b.z*b.z + b.w*b.w
                 + c.x*c.x + c.y*c.y + c.z*c.z + c.w*c.w;
        #pragma unroll
        for (int off = 32; off >= 1; off >>= 1) ss += __shfl_xor(ss, off);
        float* red = &tile[0][0];
        if ((tid & 63) == 0) red[tid >> 6] = ss;
        __syncthreads();
        const float inv = rsqrtf((red[0] + red[1] + red[2] + red[3]) * (1.0f / D_MODEL) + 1e-6f);
        const float4* sr = (const float4*)sc;
        float4 s0 = sr[tid], s1 = sr[tid + 256], s2 = sr[tid + 512];
        bf16x4* xo = (bf16x4*)(xn + (size_t)tok * D_MODEL);
        bf16x4 o;
        o[0]=(bf16_t)(a.x*s0.x*inv); o[1]=(bf16_t)(a.y*s0.y*inv); o[2]=(bf16_t)(a.z*s0.z*inv); o[3]=(bf16_t)(a.w*s0.w*inv);
        xo[tid] = o;
        o[0]=(bf16_t)(b.x*s1.x*inv); o[1]=(bf16_t)(b.y*s1.y*inv); o[2]=(bf16_t)(b.z*s1.z*inv); o[3]=(bf16_t)(b.w*s1.w*inv);
        xo[tid + 256] = o;
        o[0]=(bf16_t)(c.x*s2.x*inv); o[1]=(bf16_t)(c.y*s2.y*inv); o[2]=(bf16_t)(c.z*s2.z*inv); o[3]=(bf16_t)(c.w*s2.w*inv);
        xo[tid + 512] = o;
        return;
    }
    int t = blockIdx.x - NTOK;
    const int tx = tid & 31, ty = tid >> 5;
    if (t >= 24768) {
        const int tt = t - 24768;
        const int idx = tt * 256 + tid;
        float4 v = ((const float4*)w_o)[idx];
        bf16x4 o;
        o[0] = (bf16_t)v.x; o[1] = (bf16_t)v.y; o[2] = (bf16_t)v.z; o[3] = (bf16_t)v.w;
        ((bf16x4*)wob)[idx] = o;
        return;
    }
    const float* in; bf16_t* out; int K, N, ntx;
    if (t < 4608)        {            in = w_dq;  out = wcat;                          K = 3072; N = 1536; ntx = 48; }
    else if (t < 10944)  { t -= 4608; in = w_dkv; out = wcat + (size_t)1536 * 3072;    K = 3072; N = 2112; ntx = 66; }
    else if (t < 15552)  { t -= 10944; in = w_uq;  out = wuqt;                         K = 1536; N = 3072; ntx = 96; }
    else                 { t -= 15552; in = w_ukv; out = wukvt;                        K = 2048; N = 4608; ntx = 144; }
    const int n0 = (t % ntx) * 32, k0 = (t / ntx) * 32;
    #pragma unroll
    for (int i = 0; i < 32; i += 8)
        tile[ty + i][tx] = in[(size_t)(k0 + ty + i) * N + n0 + tx];
    __syncthreads();
    #pragma unroll
    for (int i = 0; i < 32; i += 8)
        out[(size_t)(n0 + ty + i) * K + k0 + tx] = (bf16_t)tile[tx][ty + i];
}

// ======  256xBN GEMM, counted-vmcnt 4-phase pipeline (down-proj only)  ======
template<int RH, int BNF>
__device__ __forceinline__ void mfmaQ(f32x4 (&acc)[8][BNF], const bf16x8 (&af)[4],
                                      const bf16x8 (&bfv)[BNF]) {
    __builtin_amdgcn_s_setprio(1);
    #pragma unroll
    for (int i = 0; i < 4; ++i)
        #pragma unroll
        for (int cf = 0; cf < BNF; ++cf)
            acc[RH*4+i][cf] = __builtin_amdgcn_mfma_f32_16x16x32_bf16(af[i], bfv[cf], acc[RH*4+i][cf], 0, 0, 0);
    __builtin_amdgcn_s_setprio(0);
}

template<int BNF>
__global__ __launch_bounds__(512, 2) void gemm256(
    const bf16_t* __restrict__ A, const bf16_t* __restrict__ B, int N, int K,
    float* __restrict__ Cf, int ldf, int flo, int fhi,
    bf16_t* __restrict__ Cb1, int ldb1, int b1lo, int b1hi,
    bf16_t* __restrict__ Cb2, int ldb2, int b2lo, int b2hi)
{
    constexpr int BN = BNF * 64;
    constexpr uint32_t BSLOT = BNF * 4096;
    __shared__ char LDS[65536 + 4 * BSLOT];
    char* Lc = LDS;
    const int tid = threadIdx.x;
    const int wv = tid >> 6, lane = tid & 63;
    const int fr = lane & 15, fg = lane >> 4;
    const int wr = wv >> 2, wc = wv & 3;
    const bool bwave = (wv < 2 * BNF);

    int lin = blockIdx.y * gridDim.x + blockIdx.x;
    const int nwg = gridDim.x * gridDim.y;
    if ((nwg & 7) == 0) lin = (lin & 7) * (nwg >> 3) + (lin >> 3);
    const int bx = lin % gridDim.x, by = lin / gridDim.x;
    const int m0 = by << 8, n0 = bx * BN;

    const uint32_t slot4 = (uint32_t)((fg ^ ((fr >> 1) & 3)) << 4);

    const bf16_t* agp[2]; const bf16_t* bgp[2];
    uint32_t aoff[2], boff[2];
    #pragma unroll
    for (int j = 0; j < 2; ++j) {
        const int c = j * 512 + tid;
        const int g = c ^ ((c >> 3) & 3);
        agp[j] = A + (size_t)(m0 + (g >> 2)) * K + (g & 3) * 8;
        aoff[j] = (uint32_t)((j * 8 + wv) * 1024);
        const int cb = j * (BNF * 128) + tid;
        const int gb = cb ^ ((cb >> 3) & 3);
        int br = n0 + (gb >> 2); if (br > N - 1) br = N - 1;
        bgp[j] = B + (size_t)br * K + (gb & 3) * 8;
        boff[j] = (uint32_t)(j * (BNF * 2048) + wv * 1024);
    }

    f32x4 acc[8][BNF];
    f32x4 zero = {0.f, 0.f, 0.f, 0.f};
    #pragma unroll
    for (int i = 0; i < 8; ++i)
        #pragma unroll
        for (int j = 0; j < BNF; ++j) acc[i][j] = zero;

    bf16x8 A0[4], A1[4], B0[BNF], B1[BNF];
    const int rowA = (wr << 7) + fr;
    const int rowB = wc * (BNF * 16) + fr;

    auto stA = [&](int t, int kh) {
        const uint32_t sb = (uint32_t)(((2*t + kh) & 3) << 14);
        #pragma unroll
        for (int j = 0; j < 2; ++j)
            async_ld16(agp[j] + t * 64 + kh * 32, Lc + sb + aoff[j]);
    };
    auto stB = [&](int t, int kh) {
        const uint32_t sb = 65536u + (uint32_t)(((2*t + kh) & 3) * BSLOT);
        if (tid < BNF * 128) {
            #pragma unroll
            for (int j = 0; j < 2; ++j)
                async_ld16(bgp[j] + t * 64 + kh * 32, Lc + sb + boff[j]);
        }
    };
    auto ldA4 = [&](int t, int kh, int rh, bf16x8 (&dst)[4]) {
        const uint32_t base = (uint32_t)(((2*t + kh) & 3) << 14);
        #pragma unroll
        for (int i = 0; i < 4; ++i)
            dst[i] = *(const bf16x8*)(Lc + base + (rowA + (rh * 4 + i) * 16) * 64 + slot4);
    };
    auto ldBn = [&](int t, int kh, bf16x8 (&dst)[BNF]) {
        const uint32_t base = 65536u + (uint32_t)(((2*t + kh) & 3) * BSLOT);
        #pragma unroll
        for (int cf = 0; cf < BNF; ++cf)
            dst[cf] = *(const bf16x8*)(Lc + base + (rowB + cf * 16) * 64 + slot4);
    };

    const int NT = K >> 6;
    stA(0, 0); stB(0, 0); stA(0, 1); stB(0, 1);
    stA(1, 0); stB(1, 0); stA(1, 1); stB(1, 1);
    if (bwave) { WAITVN(8); } else { WAITVN(4); }
    BARRIER();
    ldA4(0, 0, 0, A0); ldBn(0, 0, B0);

    for (int t = 0; t < NT; ++t) {
        const bool pref = (t + 2 < NT);
        ldA4(t, 0, 1, A1);
        mfmaQ<0, BNF>(acc, A0, B0);
        if (pref) { if (bwave) { WAITVN(4); } else { WAITVN(2); } }
        else      { WAITVN(0); }
        BARRIER();
        ldA4(t, 1, 0, A0); ldBn(t, 1, B1);
        if (pref) { stA(t + 2, 0); stB(t + 2, 0); }
        mfmaQ<1, BNF>(acc, A1, B0);
        BARRIER();
        ldA4(t, 1, 1, A1);
        mfmaQ<0, BNF>(acc, A0, B1);
        BARRIER();
        if (t + 1 < NT) { ldA4(t + 1, 0, 0, A0); ldBn(t + 1, 0, B0); }
        if (pref) { stA(t + 2, 1); stB(t + 2, 1); }
        mfmaQ<1, BNF>(acc, A1, B1);
        BARRIER();
    }

    const int colb = n0 + wc * (BNF * 16) + fr;
    const int rowb = m0 + (wr << 7) + fg * 4;
    #pragma unroll
    for (int rf = 0; rf < 8; ++rf)
        #pragma unroll
        for (int cf = 0; cf < BNF; ++cf) {
            const int col = colb + cf * 16;
            #pragma unroll
            for (int r = 0; r < 4; ++r) {
                const int row = rowb + rf * 16 + r;
                const float v = acc[rf][cf][r];
                if (Cf  && col >= flo  && col < fhi)  Cf [(size_t)row * ldf  + col - flo]  = v;
                if (Cb1 && col >= b1lo && col < b1hi) Cb1[(size_t)row * ldb1 + col - b1lo] = (bf16_t)v;
                if (Cb2 && col >= b2lo && col < b2hi) Cb2[(size_t)row * ldb2 + col - b2lo] = (bf16_t)v;
            }
        }
}

// ======  128x192 GEMM, counted-vmcnt loop, 80KB LDS -> 2 blocks/CU  ======
template<int RH>
__device__ __forceinline__ void mfmaH(f32x4 (&acc)[4][3], const bf16x8 (&af)[2],
                                      const bf16x8 (&bfv)[3]) {
    __builtin_amdgcn_s_setprio(1);
    #pragma unroll
    for (int i = 0; i < 2; ++i)
        #pragma unroll
        for (int cf = 0; cf < 3; ++cf)
            acc[RH*2+i][cf] = __builtin_amdgcn_mfma_f32_16x16x32_bf16(af[i], bfv[cf], acc[RH*2+i][cf], 0, 0, 0);
    __builtin_amdgcn_s_setprio(0);
}

__global__ __launch_bounds__(512, 4) void gemm128(
    const bf16_t* __restrict__ A, const bf16_t* __restrict__ B, int N, int K,
    float* __restrict__ Cf, int ldf,
    bf16_t* __restrict__ Cb1, int ldb1,
    bf16_t* __restrict__ vt, float cbscale)
{
    __shared__ char LDS[32768 + 49152];        // A-ring 4x8KB, B-ring 4x12KB
    char* Lc = LDS;
    const int tid = threadIdx.x;
    const int wv = tid >> 6, lane = tid & 63;
    const int fr = lane & 15, fg = lane >> 4;
    const int wr = wv >> 2, wc = wv & 3;
    const bool bwave = (wv < 6);

    int lin = blockIdx.y * gridDim.x + blockIdx.x;
    const int nwg = gridDim.x * gridDim.y;
    if ((nwg & 7) == 0) lin = (lin & 7) * (nwg >> 3) + (lin >> 3);
    const int bx = lin % gridDim.x, by = lin / gridDim.x;
    const int m0 = by << 7, n0 = bx * 192;

    const uint32_t slot4 = (uint32_t)((fg ^ ((fr >> 1) & 3)) << 4);

    const int ga = tid ^ ((tid >> 3) & 3);
    const bf16_t* agp = A + (size_t)(m0 + (ga >> 2)) * K + (ga & 3) * 8;
    const uint32_t aoff = (uint32_t)(wv * 1024);
    const bf16_t* bgp[2]; uint32_t boff[2];
    #pragma unroll
    for (int j = 0; j < 2; ++j) {
        const int cb = j * 384 + tid;
        const int gb = cb ^ ((cb >> 3) & 3);
        int br = n0 + (gb >> 2); if (br > N - 1) br = N - 1;
        bgp[j] = B + (size_t)br * K + (gb & 3) * 8;
        boff[j] = (uint32_t)(j * 6144 + wv * 1024);
    }

    f32x4 acc[4][3];
    f32x4 zero = {0.f, 0.f, 0.f, 0.f};
    #pragma unroll
    for (int i = 0; i < 4; ++i)
        #pragma unroll
        for (int j = 0; j < 3; ++j) acc[i][j] = zero;

    bf16x8 A0[2], A1[2], B0[3], B1[3];
    const int rowA = (wr << 6) + fr;
    const int rowB = wc * 48 + fr;

    auto stA = [&](int t, int kh) {
        const uint32_t sb = (uint32_t)(((2*t + kh) & 3) << 13);
        async_ld16(agp + t * 64 + kh * 32, Lc + sb + aoff);
    };
    auto stB = [&](int t, int kh) {
        const uint32_t sb = 32768u + (uint32_t)(((2*t + kh) & 3) * 12288);
        if (tid < 384) {
            #pragma unroll
            for (int j = 0; j < 2; ++j)
                async_ld16(bgp[j] + t * 64 + kh * 32, Lc + sb + boff[j]);
        }
    };
    auto ldA2 = [&](int t, int kh, int rh, bf16x8 (&dst)[2]) {
        const uint32_t base = (uint32_t)(((2*t + kh) & 3) << 13);
        #pragma unroll
        for (int i = 0; i < 2; ++i)
            dst[i] = *(const bf16x8*)(Lc + base + (rowA + (rh * 2 + i) * 16) * 64 + slot4);
    };
    auto ldB3 = [&](int t, int kh, bf16x8 (&dst)[3]) {
        const uint32_t base = 32768u + (uint32_t)(((2*t + kh) & 3) * 12288);
        #pragma unroll
        for (int cf = 0; cf < 3; ++cf)
            dst[cf] = *(const bf16x8*)(Lc + base + (rowB + cf * 16) * 64 + slot4);
    };

    const int NT = K >> 6;
    stA(0, 0); stB(0, 0); stA(0, 1); stB(0, 1);
    stA(1, 0); stB(1, 0); stA(1, 1); stB(1, 1);
    if (bwave) { WAITVN(6); } else { WAITVN(2); }
    BARRIER();
    ldA2(0, 0, 0, A0); ldB3(0, 0, B0);

    for (int t = 0; t < NT; ++t) {
        const bool pref = (t + 2 < NT);
        ldA2(t, 0, 1, A1);
        mfmaH<0>(acc, A0, B0);
        if (pref) { if (bwave) { WAITVN(3); } else { WAITVN(1); } }
        else      { WAITVN(0); }
        BARRIER();
        ldA2(t, 1, 0, A0); ldB3(t, 1, B1);
        if (pref) { stA(t + 2, 0); stB(t + 2, 0); }
        mfmaH<1>(acc, A1, B0);
        BARRIER();
        ldA2(t, 1, 1, A1);
        mfmaH<0>(acc, A0, B1);
        BARRIER();
        if (t + 1 < NT) { ldA2(t + 1, 0, 0, A0); ldB3(t + 1, 0, B0); }
        if (pref) { stA(t + 2, 1); stB(t + 2, 1); }
        mfmaH<1>(acc, A1, B1);
        BARRIER();
    }

    const int colb = n0 + wc * 48 + fr;
    const int rowb = m0 + (wr << 6) + fg * 4;
    if (vt) {
        #pragma unroll
        for (int rf = 0; rf < 4; ++rf) {
            const int row0 = rowb + rf * 16;
            const int bb = row0 >> 11, s0 = row0 & 2047;
            #pragma unroll
            for (int cf = 0; cf < 3; ++cf) {
                const int col = colb + cf * 16;
                const int h = col / 192;
                const int dm = col - h * 192;
                if (dm < 64) {
                    #pragma unroll
                    for (int r = 0; r < 4; ++r)
                        Cb1[(size_t)(row0 + r) * ldb1 + col] = (bf16_t)acc[rf][cf][r];
                } else {
                    bf16x4 o;
                    o[0] = (bf16_t)acc[rf][cf][0];
                    o[1] = (bf16_t)acc[rf][cf][1];
                    o[2] = (bf16_t)acc[rf][cf][2];
                    o[3] = (bf16_t)acc[rf][cf][3];
                    *(bf16x4*)(vt + ((size_t)((bb * 24 + h) * 128 + dm - 64)) * 2048 + s0) = o;
                }
            }
        }
    } else {
        #pragma unroll
        for (int rf = 0; rf < 4; ++rf)
            #pragma unroll
            for (int cf = 0; cf < 3; ++cf) {
                const int col = colb + cf * 16;
                #pragma unroll
                for (int r = 0; r < 4; ++r) {
                    const int row = rowb + rf * 16 + r;
                    const float v = acc[rf][cf][r];
                    if (Cf)  Cf [(size_t)row * ldf  + col] = v;
                    if (Cb1) Cb1[(size_t)row * ldb1 + col] = (bf16_t)(v * cbscale);
                }
            }
    }
}

// =========================  RoPE tables (fp32)  =========================
__global__ void rope_tab(float* __restrict__ ctab, float* __restrict__ stab)
{
    const int idx = blockIdx.x * 256 + threadIdx.x;
    if (idx >= S_LEN * 32) return;
    const int s = idx >> 5, i = idx & 31;
    const float freq = powf(10000.0f, -(float)(2 * i) * (1.0f / 128.0f));
    const float ang = (float)s * freq;
    ctab[idx] = cosf(ang);
    stab[idx] = sinf(ang);
}

// ====  unified RoPE: Q (vectorized bf16x8, in-place) + shared K-rope  ====
__global__ __launch_bounds__(256) void rope_all(
    bf16_t* __restrict__ q, const float* __restrict__ kvd, bf16_t* __restrict__ kr,
    const float* __restrict__ ctab, const float* __restrict__ stab)
{
    const int idx = blockIdx.x * 256 + threadIdx.x;
    if (idx < NTOK * N_HEADS * 4) {
        const int c = idx & 3;
        const int rest = idx >> 2;
        const int h = rest % N_HEADS;
        const int tok = rest / N_HEADS;
        const int s = tok & (S_LEN - 1);
        bf16_t* p = q + (size_t)tok * D_MODEL + h * HEAD_DIM + 64 + c * 8;
        bf16x8 a = *(const bf16x8*)(p);
        bf16x8 b = *(const bf16x8*)(p + 32);
        const float4* cp = (const float4*)(ctab + s * 32 + c * 8);
        const float4* sp = (const float4*)(stab + s * 32 + c * 8);
        float4 c0 = cp[0], c1 = cp[1];
        float4 s0 = sp[0], s1 = sp[1];
        float cs[8] = {c0.x, c0.y, c0.z, c0.w, c1.x, c1.y, c1.z, c1.w};
        float sn[8] = {s0.x, s0.y, s0.z, s0.w, s1.x, s1.y, s1.z, s1.w};
        bf16x8 oa, ob;
        #pragma unroll
        for (int j = 0; j < 8; ++j) {
            const float av = (float)a[j], bv = (float)b[j];
            oa[j] = (bf16_t)(av * cs[j] - bv * sn[j]);
            ob[j] = (bf16_t)(bv * cs[j] + av * sn[j]);
        }
        *(bf16x8*)(p)      = oa;
        *(bf16x8*)(p + 32) = ob;
    } else {
        const int kx = idx - NTOK * N_HEADS * 4;
        if (kx >= NTOK * 32) return;
        const int i = kx & 31;
        const int tok = kx >> 5;
        const int s = tok & (S_LEN - 1);
        const float* p = kvd + (size_t)tok * KVDN + KV_PROJ;
        const float a = p[i], b = p[i + 32];
        const float c = ctab[s * 32 + i], sn = stab[s * 32 + i];
        kr[(size_t)tok * 64 + i]      = (bf16_t)(a * c - b * sn);
        kr[(size_t)tok * 64 + i + 32] = (bf16_t)(b * c + a * sn);
    }
}

// ======  causal flash attention (R8 body; balanced 3-job grid of 256 blocks)  ======
// Jobs (bh, qt): block handles 3 jobs with qt from row r of the balanced table
// {r, (r+8)&15, r<8?14-2r:31-2r} (sums 22/23 -> 50/52 kv-steps per block).
// XCD-aware: group of 16 blocks (3 bhs) lands on one XCD's L2.
// Q pre-scaled by (1/sqrt(128))*log2(e).
__global__ __launch_bounds__(256, 2) void attn_fwd(
    const bf16_t* __restrict__ Q, const bf16_t* __restrict__ KVUP,
    const bf16_t* __restrict__ KR, const bf16_t* __restrict__ VT,
    bf16_t* __restrict__ AO)
{
    __shared__ bf16_t Knr[2][64 * 64];
    __shared__ bf16_t Krp[2][64 * 64];
    __shared__ bf16_t Vls[2][128 * 64];

    const int wave = threadIdx.x >> 6, lane = threadIdx.x & 63;
    const int fr = lane & 15, fg = lane >> 4;
    const int rx = fr & 7;
    const int hi = fg >> 1;
    const int s0l = fr + 32 * (fg & 1);
    const int s1l = s0l + 16;

    // balanced job table (see header comment)
    const int xc = blockIdx.x & 7, qd = blockIdx.x >> 3;
    const int grp = xc * 2 + (qd >> 4), r = qd & 15;
    const int p2qt = (r < 8) ? (14 - 2 * r) : (31 - 2 * r);

    const int srow   = lane >> 3;
    const int schunk = (lane & 7) ^ srow;

    f32x4 zero = {0.f, 0.f, 0.f, 0.f};

    #pragma unroll 1
    for (int jj = 0; jj < 3; ++jj) {
        const int bh = grp * 3 + jj;
        const int b = bh / N_HEADS, h = bh % N_HEADS;
        const int qt = (jj == 0) ? r : (jj == 1) ? ((r + 8) & 15) : p2qt;
        const int qb = qt * 128;
        const int wrow0 = qb + wave * 32;

        const bf16_t* Kb  = KVUP + (size_t)b * S_LEN * KVUN + (size_t)h * 192;
        const bf16_t* KRb = KR + (size_t)b * S_LEN * 64;
        const bf16_t* Vb  = VT + (size_t)bh * HEAD_DIM * S_LEN;

        bf16x8 qf[2][4];
        #pragma unroll
        for (int rf = 0; rf < 2; ++rf)
            #pragma unroll
            for (int kc = 0; kc < 4; ++kc)
                qf[rf][kc] = *(const bf16x8*)(Q + (size_t)(b * S_LEN + wrow0 + rf * 16 + fr) * D_MODEL
                                              + h * HEAD_DIM + kc * 32 + fg * 8);
        f32x4 oacc[2][8];
        float m_i[2], l_i[2];
        #pragma unroll
        for (int rf = 0; rf < 2; ++rf) {
            #pragma unroll
            for (int nf = 0; nf < 8; ++nf) oacc[rf][nf] = zero;
            m_i[rf] = -1e30f; l_i[rf] = 0.f;
        }

        auto stage = [&](int kvb, int bf) {
            #pragma unroll
            for (int c = 0; c < 2; ++c) {
                const int r0 = wave * 16 + c * 8;
                async_ld16(Kb  + (size_t)(kvb + r0 + srow) * KVUN + schunk * 8, &Knr[bf][r0 * 64]);
                async_ld16(KRb + (size_t)(kvb + r0 + srow) * 64   + schunk * 8, &Krp[bf][r0 * 64]);
            }
            #pragma unroll
            for (int c = 0; c < 4; ++c) {
                const int r0 = wave * 32 + c * 8;
                async_ld16(Vb + (size_t)(r0 + srow) * S_LEN + kvb + schunk * 8, &Vls[bf][r0 * 64]);
            }
        };

        const int kvend = qb + 128;
        int cur = 0;
        stage(0, 0);
        __syncthreads();

        #pragma unroll 1
        for (int kvb = 0; kvb < kvend; kvb += 64) {
            if (kvb + 64 < kvend) stage(kvb + 64, cur ^ 1);

            if (kvb <= wrow0 + 31) {
                const bf16_t* Kc = Knr[cur];
                const bf16_t* Rc = Krp[cur];
                const bf16_t* Vc = Vls[cur];

                f32x4 sacc[2][4];
                #pragma unroll
                for (int rf = 0; rf < 2; ++rf)
                    #pragma unroll
                    for (int jn = 0; jn < 4; ++jn) sacc[rf][jn] = zero;
                __builtin_amdgcn_s_setprio(1);
                #pragma unroll
                for (int jn = 0; jn < 4; ++jn) {
                    const int krow = jn * 16 + fr;
                    bf16x8 kA = *(const bf16x8*)(Kc + krow * 64 + (((0 + fg) ^ rx) << 3));
                    bf16x8 kB = *(const bf16x8*)(Kc + krow * 64 + (((4 + fg) ^ rx) << 3));
                    bf16x8 kC = *(const bf16x8*)(Rc + krow * 64 + (((0 + fg) ^ rx) << 3));
                    bf16x8 kD = *(const bf16x8*)(Rc + krow * 64 + (((4 + fg) ^ rx) << 3));
                    #pragma unroll
                    for (int rf = 0; rf < 2; ++rf) {
                        sacc[rf][jn] = __builtin_amdgcn_mfma_f32_16x16x32_bf16(kA, qf[rf][0], sacc[rf][jn], 0, 0, 0);
                        sacc[rf][jn] = __builtin_amdgcn_mfma_f32_16x16x32_bf16(kB, qf[rf][1], sacc[rf][jn], 0, 0, 0);
                        sacc[rf][jn] = __builtin_amdgcn_mfma_f32_16x16x32_bf16(kC, qf[rf][2], sacc[rf][jn], 0, 0, 0);
                        sacc[rf][jn] = __builtin_amdgcn_mfma_f32_16x16x32_bf16(kD, qf[rf][3], sacc[rf][jn], 0, 0, 0);
                    }
                }
                __builtin_amdgcn_s_setprio(0);

                const bool needMask = (kvb + 63 > wrow0);
                uint32_t pk[2][4][2];
                #pragma unroll
                for (int rf = 0; rf < 2; ++rf) {
                    const int qrow = wrow0 + rf * 16 + fr;
                    float mx = -1e30f;
                    #pragma unroll
                    for (int jn = 0; jn < 4; ++jn)
                        #pragma unroll
                        for (int rr = 0; rr < 4; ++rr) {
                            float v = sacc[rf][jn][rr];
                            if (needMask && (kvb + jn * 16 + fg * 4 + rr > qrow)) v = -1e30f;
                            sacc[rf][jn][rr] = v;
                            mx = fmaxf(mx, v);
                        }
                    mx = fmaxf(mx, __shfl_xor(mx, 16));
                    mx = fmaxf(mx, __shfl_xor(mx, 32));
                    if (!__all(mx <= m_i[rf] + 8.f)) {
                        const float mn = fmaxf(m_i[rf], mx);
                        const float sc = __builtin_amdgcn_exp2f(m_i[rf] - mn);
                        m_i[rf] = mn;
                        l_i[rf] *= sc;
                        #pragma unroll
                        for (int nf = 0; nf < 8; ++nf)
                            #pragma unroll
                            for (int rr = 0; rr < 4; ++rr) oacc[rf][nf][rr] *= sc;
                    }
                    const float mn = m_i[rf];
                    float ls = 0.f;
                    #pragma unroll
                    for (int jn = 0; jn < 4; ++jn) {
                        float p0 = __builtin_amdgcn_exp2f(sacc[rf][jn][0] - mn);
                        float p1 = __builtin_amdgcn_exp2f(sacc[rf][jn][1] - mn);
                        float p2 = __builtin_amdgcn_exp2f(sacc[rf][jn][2] - mn);
                        float p3 = __builtin_amdgcn_exp2f(sacc[rf][jn][3] - mn);
                        ls += (p0 + p1) + (p2 + p3);
                        union { bf16x4 h; uint32_t w[2]; } cv;
                        cv.h[0] = (bf16_t)p0; cv.h[1] = (bf16_t)p1;
                        cv.h[2] = (bf16_t)p2; cv.h[3] = (bf16_t)p3;
                        pk[rf][jn][0] = cv.w[0]; pk[rf][jn][1] = cv.w[1];
                    }
                    ls += __shfl_xor(ls, 16);
                    ls += __shfl_xor(ls, 32);
                    l_i[rf] += ls;
                }

                bf16x8 bfr[2][2];
                #pragma unroll
                for (int rf = 0; rf < 2; ++rf)
                    #pragma unroll
                    for (int ks = 0; ks < 2; ++ks) {
                        const uint32_t t00 = __shfl(pk[rf][2*ks][0],   s0l);
                        const uint32_t t01 = __shfl(pk[rf][2*ks][1],   s0l);
                        const uint32_t t10 = __shfl(pk[rf][2*ks+1][0], s0l);
                        const uint32_t t11 = __shfl(pk[rf][2*ks+1][1], s0l);
                        const uint32_t u00 = __shfl(pk[rf][2*ks][0],   s1l);
                        const uint32_t u01 = __shfl(pk[rf][2*ks][1],   s1l);
                        const uint32_t u10 = __shfl(pk[rf][2*ks+1][0], s1l);
                        const uint32_t u11 = __shfl(pk[rf][2*ks+1][1], s1l);
                        union { bf16x8 h; uint32_t w[4]; } bb;
                        bb.w[0] = hi ? t10 : t00;
                        bb.w[1] = hi ? t11 : t01;
                        bb.w[2] = hi ? u10 : u00;
                        bb.w[3] = hi ? u11 : u01;
                        bfr[rf][ks] = bb.h;
                    }

                __builtin_amdgcn_s_setprio(1);
                #pragma unroll
                for (int nf = 0; nf < 8; ++nf) {
                    const int vrow = nf * 16 + fr;
                    bf16x8 v0 = *(const bf16x8*)(Vc + vrow * 64 + (((0 + fg) ^ rx) << 3));
                    bf16x8 v1 = *(const bf16x8*)(Vc + vrow * 64 + (((4 + fg) ^ rx) << 3));
                    #pragma unroll
                    for (int rf = 0; rf < 2; ++rf) {
                        oacc[rf][nf] = __builtin_amdgcn_mfma_f32_16x16x32_bf16(v0, bfr[rf][0], oacc[rf][nf], 0, 0, 0);
                        oacc[rf][nf] = __builtin_amdgcn_mfma_f32_16x16x32_bf16(v1, bfr[rf][1], oacc[rf][nf], 0, 0, 0);
                    }
                }
                __builtin_amdgcn_s_setprio(0);
            }
            __syncthreads();
            cur ^= 1;
        }

        #pragma unroll
        for (int rf = 0; rf < 2; ++rf) {
            const float rl = __builtin_amdgcn_rcpf(l_i[rf]);
            const int qrow = wrow0 + rf * 16 + fr;
            bf16_t* aob = AO + (size_t)(b * S_LEN + qrow) * D_MODEL + h * HEAD_DIM + fg * 4;
            #pragma unroll
            for (int nf = 0; nf < 8; ++nf) {
                bf16x4 o;
                o[0] = (bf16_t)(oacc[rf][nf][0] * rl);
                o[1] = (bf16_t)(oacc[rf][nf][1] * rl);
                o[2] = (bf16_t)(oacc[rf][nf][2] * rl);
                o[3] = (bf16_t)(oacc[rf][nf][3] * rl);
                *(bf16x4*)(aob + nf * 16) = o;
            }
        }
    }
}

// ============================  launch  ============================
extern "C" void kernel_launch(void* const* d_in, const int* in_sizes, int n_in,
                              void* d_out, int out_size, void* d_ws, size_t ws_size,
                              hipStream_t stream)
{
    const float* x     = (const float*)d_in[0];
    const float* scale = (const float*)d_in[1];
    const float* w_dq  = (const float*)d_in[2];
    const float* w_uq  = (const float*)d_in[3];
    const float* w_dkv = (const float*)d_in[4];
    const float* w_ukv = (const float*)d_in[5];
    const float* w_o   = (const float*)d_in[6];
    float* out0 = (float*)d_out;                        // (4096, 3072)
    float* out1 = out0 + (size_t)NTOK * D_MODEL;        // (4096, 2112)

    if (ws_size < 187039744ull) return;
    char* ws = (char*)d_ws;
    bf16_t* XN    = (bf16_t*)(ws + 0);
    bf16_t* WCAT  = (bf16_t*)(ws + 25165824ull);        // [3648][3072] b^T (dq|dkv)
    bf16_t* WUQT  = (bf16_t*)(ws + 47579136ull);
    bf16_t* WUKVT = (bf16_t*)(ws + 57016320ull);
    bf16_t* WOB   = (bf16_t*)(ws + 75890688ull);
    bf16_t* QD    = (bf16_t*)(ws + 94765056ull);
    bf16_t* Qb    = (bf16_t*)(ws + 107347968ull);
    bf16_t* KVNR  = (bf16_t*)(ws + 132513792ull);
    bf16_t* KVUP  = (bf16_t*)(ws + 149291008ull);
    bf16_t* KRB   = (bf16_t*)(ws + 94765056ull);        // aliases QD (after q_up)
    float*  CTAB  = (float*) (ws + 95289344ull);        // in QD region (after q_up)
    float*  STAB  = (float*) (ws + 95551488ull);
    bf16_t* VTb   = WCAT;                               // reuses WCAT (after down-proj)
    bf16_t* AO    = XN;

    const float l2e_isc = 0.127500625f;                 // (1/sqrt(128)) * log2(e)

    // fused pre-pass: RMSNorm (4096 blocks) + weight prep (33984 blocks)
    fused_pre<<<NTOK + 33984, 256, 0, stream>>>(x, scale, XN,
        w_dq, w_uq, w_dkv, w_ukv, w_o, WCAT, WUQT, WUKVT, WOB);

    // fused down-proj: N=3648, BN=256, grid 240 (1 gen) — R14 proven config
    gemm256<4><<<dim3(15, 16), 512, 0, stream>>>(XN, WCAT, 3648, 3072,
        out1, KVDN, 1536, 3648,
        QD,   Q_PROJ, 0, 1536,
        KVNR, KV_PROJ, 1536, 3584);
    // q_up: 128x192 tiles, grid 16x32 = 512 blocks (2/CU); prescaled output
    gemm128<<<dim3(16, 32), 512, 0, stream>>>(QD, WUQT, 3072, 1536,
        nullptr, 0, Qb, D_MODEL, nullptr, l2e_isc);
    rope_tab<<<(S_LEN * 32 + 255) / 256, 256, 0, stream>>>(CTAB, STAB);
    rope_all<<<2048, 256, 0, stream>>>(Qb, out1, KRB, CTAB, STAB);
    // kv_up: 128x192 tiles, grid 24x32 = 768 blocks; fused V-transpose epilogue
    gemm128<<<dim3(24, 32), 512, 0, stream>>>(KVNR, WUKVT, 4608, 2048,
        nullptr, 0, KVUP, KVUN, VTb, 1.0f);
    // balanced attn: 256 blocks x 3 jobs (50/52 steps each)
    attn_fwd<<<256, 256, 0, stream>>>(Qb, KVUP, KRB, VTb, AO);
    // output projection: 128x192 tiles, grid 16x32
    gemm128<<<dim3(16, 32), 512, 0, stream>>>(AO, WOB, 3072, 3072,
        out0, D_MODEL, nullptr, 0, nullptr, 1.0f);
}

// Round 19
// 494.980 us; speedup vs baseline: 1.0291x; 1.0291x over previous
//
#include <hip/hip_runtime.h>
#include <hip/hip_bf16.h>
#include <stdint.h>

using bf16_t = __bf16;
using bf16x8 = __attribute__((ext_vector_type(8))) __bf16;
using bf16x4 = __attribute__((ext_vector_type(4))) __bf16;
using f32x4  = __attribute__((ext_vector_type(4))) float;

#define D_MODEL 3072
#define N_HEADS 24
#define HEAD_DIM 128
#define Q_PROJ 1536
#define KV_PROJ 2048
#define ROPE_DIM 64
#define S_LEN 2048
#define NTOK 4096            // B*S
#define KVDN 2112            // KV_PROJ + ROPE_DIM
#define KVUN 4608            // D_MODEL + N_HEADS*ROPE_DIM

// ---- async global->LDS (16B per lane, wave-uniform LDS base) ----
__device__ __forceinline__ void async_ld16(const void* g, void* l) {
    __builtin_amdgcn_global_load_lds(
        (__attribute__((address_space(1))) uint32_t*)(uintptr_t)g,
        (__attribute__((address_space(3))) uint32_t*)(uint32_t)(uintptr_t)l,
        16, 0, 0);
}

#define BARRIER() __builtin_amdgcn_s_barrier()
#define WAITVN(n) asm volatile("s_waitcnt vmcnt(" #n ")" ::: "memory")

// ==  fused pre-pass: RMSNorm (blocks 0..4095) + weight prep (blocks 4096..38079)  ==
__global__ __launch_bounds__(256) void fused_pre(
    const float* __restrict__ x, const float* __restrict__ sc, bf16_t* __restrict__ xn,
    const float* __restrict__ w_dq, const float* __restrict__ w_uq,
    const float* __restrict__ w_dkv, const float* __restrict__ w_ukv,
    const float* __restrict__ w_o,
    bf16_t* __restrict__ wcat, bf16_t* __restrict__ wuqt,
    bf16_t* __restrict__ wukvt, bf16_t* __restrict__ wob)
{
    __shared__ float tile[32][33];
    const int tid = threadIdx.x;
    if (blockIdx.x < NTOK) {
        const int tok = blockIdx.x;
        const float4* xr = (const float4*)(x + (size_t)tok * D_MODEL);
        float4 a = xr[tid], b = xr[tid + 256], c = xr[tid + 512];
        float ss = a.x*a.x + a.y*a.y + a.z*a.z + a.w*a.w
                 + b.x*b.x + b.y*b.y + b.z*b.z + b.w*b.w
                 + c.x*c.x + c.y*c.y + c.z*c.z + c.w*c.w;
        #pragma unroll
        for (int off = 32; off >= 1; off >>= 1) ss += __shfl_xor(ss, off);
        float* red = &tile[0][0];
        if ((tid & 63) == 0) red[tid >> 6] = ss;
        __syncthreads();
        const float inv = rsqrtf((red[0] + red[1] + red[2] + red[3]) * (1.0f / D_MODEL) + 1e-6f);
        const float4* sr = (const float4*)sc;
        float4 s0 = sr[tid], s1 = sr[tid + 256], s2 = sr[tid + 512];
        bf16x4* xo = (bf16x4*)(xn + (size_t)tok * D_MODEL);
        bf16x4 o;
        o[0]=(bf16_t)(a.x*s0.x*inv); o[1]=(bf16_t)(a.y*s0.y*inv); o[2]=(bf16_t)(a.z*s0.z*inv); o[3]=(bf16_t)(a.w*s0.w*inv);
        xo[tid] = o;
        o[0]=(bf16_t)(b.x*s1.x*inv); o[1]=(bf16_t)(b.y*s1.y*inv); o[2]=(bf16_t)(b.z*s1.z*inv); o[3]=(bf16_t)(b.w*s1.w*inv);
        xo[tid + 256] = o;
        o[0]=(bf16_t)(c.x*s2.x*inv); o[1]=(bf16_t)(c.y*s2.y*inv); o[2]=(bf16_t)(c.z*s2.z*inv); o[3]=(bf16_t)(c.w*s2.w*inv);
        xo[tid + 512] = o;
        return;
    }
    int t = blockIdx.x - NTOK;
    const int tx = tid & 31, ty = tid >> 5;
    if (t >= 24768) {
        const int tt = t - 24768;
        const int idx = tt * 256 + tid;
        float4 v = ((const float4*)w_o)[idx];
        bf16x4 o;
        o[0] = (bf16_t)v.x; o[1] = (bf16_t)v.y; o[2] = (bf16_t)v.z; o[3] = (bf16_t)v.w;
        ((bf16x4*)wob)[idx] = o;
        return;
    }
    const float* in; bf16_t* out; int K, N, ntx;
    if (t < 4608)        {            in = w_dq;  out = wcat;                          K = 3072; N = 1536; ntx = 48; }
    else if (t < 10944)  { t -= 4608; in = w_dkv; out = wcat + (size_t)1536 * 3072;    K = 3072; N = 2112; ntx = 66; }
    else if (t < 15552)  { t -= 10944; in = w_uq;  out = wuqt;                         K = 1536; N = 3072; ntx = 96; }
    else                 { t -= 15552; in = w_ukv; out = wukvt;                        K = 2048; N = 4608; ntx = 144; }
    const int n0 = (t % ntx) * 32, k0 = (t / ntx) * 32;
    #pragma unroll
    for (int i = 0; i < 32; i += 8)
        tile[ty + i][tx] = in[(size_t)(k0 + ty + i) * N + n0 + tx];
    __syncthreads();
    #pragma unroll
    for (int i = 0; i < 32; i += 8)
        out[(size_t)(n0 + ty + i) * K + k0 + tx] = (bf16_t)tile[tx][ty + i];
}

// ======  256xBN GEMM, counted-vmcnt 4-phase pipeline (down-proj only)  ======
template<int RH, int BNF>
__device__ __forceinline__ void mfmaQ(f32x4 (&acc)[8][BNF], const bf16x8 (&af)[4],
                                      const bf16x8 (&bfv)[BNF]) {
    __builtin_amdgcn_s_setprio(1);
    #pragma unroll
    for (int i = 0; i < 4; ++i)
        #pragma unroll
        for (int cf = 0; cf < BNF; ++cf)
            acc[RH*4+i][cf] = __builtin_amdgcn_mfma_f32_16x16x32_bf16(af[i], bfv[cf], acc[RH*4+i][cf], 0, 0, 0);
    __builtin_amdgcn_s_setprio(0);
}

template<int BNF>
__global__ __launch_bounds__(512, 2) void gemm256(
    const bf16_t* __restrict__ A, const bf16_t* __restrict__ B, int N, int K,
    float* __restrict__ Cf, int ldf, int flo, int fhi,
    bf16_t* __restrict__ Cb1, int ldb1, int b1lo, int b1hi,
    bf16_t* __restrict__ Cb2, int ldb2, int b2lo, int b2hi)
{
    constexpr int BN = BNF * 64;
    constexpr uint32_t BSLOT = BNF * 4096;
    __shared__ char LDS[65536 + 4 * BSLOT];
    char* Lc = LDS;
    const int tid = threadIdx.x;
    const int wv = tid >> 6, lane = tid & 63;
    const int fr = lane & 15, fg = lane >> 4;
    const int wr = wv >> 2, wc = wv & 3;
    const bool bwave = (wv < 2 * BNF);

    int lin = blockIdx.y * gridDim.x + blockIdx.x;
    const int nwg = gridDim.x * gridDim.y;
    if ((nwg & 7) == 0) lin = (lin & 7) * (nwg >> 3) + (lin >> 3);
    const int bx = lin % gridDim.x, by = lin / gridDim.x;
    const int m0 = by << 8, n0 = bx * BN;

    const uint32_t slot4 = (uint32_t)((fg ^ ((fr >> 1) & 3)) << 4);

    const bf16_t* agp[2]; const bf16_t* bgp[2];
    uint32_t aoff[2], boff[2];
    #pragma unroll
    for (int j = 0; j < 2; ++j) {
        const int c = j * 512 + tid;
        const int g = c ^ ((c >> 3) & 3);
        agp[j] = A + (size_t)(m0 + (g >> 2)) * K + (g & 3) * 8;
        aoff[j] = (uint32_t)((j * 8 + wv) * 1024);
        const int cb = j * (BNF * 128) + tid;
        const int gb = cb ^ ((cb >> 3) & 3);
        int br = n0 + (gb >> 2); if (br > N - 1) br = N - 1;
        bgp[j] = B + (size_t)br * K + (gb & 3) * 8;
        boff[j] = (uint32_t)(j * (BNF * 2048) + wv * 1024);
    }

    f32x4 acc[8][BNF];
    f32x4 zero = {0.f, 0.f, 0.f, 0.f};
    #pragma unroll
    for (int i = 0; i < 8; ++i)
        #pragma unroll
        for (int j = 0; j < BNF; ++j) acc[i][j] = zero;

    bf16x8 A0[4], A1[4], B0[BNF], B1[BNF];
    const int rowA = (wr << 7) + fr;
    const int rowB = wc * (BNF * 16) + fr;

    auto stA = [&](int t, int kh) {
        const uint32_t sb = (uint32_t)(((2*t + kh) & 3) << 14);
        #pragma unroll
        for (int j = 0; j < 2; ++j)
            async_ld16(agp[j] + t * 64 + kh * 32, Lc + sb + aoff[j]);
    };
    auto stB = [&](int t, int kh) {
        const uint32_t sb = 65536u + (uint32_t)(((2*t + kh) & 3) * BSLOT);
        if (tid < BNF * 128) {
            #pragma unroll
            for (int j = 0; j < 2; ++j)
                async_ld16(bgp[j] + t * 64 + kh * 32, Lc + sb + boff[j]);
        }
    };
    auto ldA4 = [&](int t, int kh, int rh, bf16x8 (&dst)[4]) {
        const uint32_t base = (uint32_t)(((2*t + kh) & 3) << 14);
        #pragma unroll
        for (int i = 0; i < 4; ++i)
            dst[i] = *(const bf16x8*)(Lc + base + (rowA + (rh * 4 + i) * 16) * 64 + slot4);
    };
    auto ldBn = [&](int t, int kh, bf16x8 (&dst)[BNF]) {
        const uint32_t base = 65536u + (uint32_t)(((2*t + kh) & 3) * BSLOT);
        #pragma unroll
        for (int cf = 0; cf < BNF; ++cf)
            dst[cf] = *(const bf16x8*)(Lc + base + (rowB + cf * 16) * 64 + slot4);
    };

    const int NT = K >> 6;
    stA(0, 0); stB(0, 0); stA(0, 1); stB(0, 1);
    stA(1, 0); stB(1, 0); stA(1, 1); stB(1, 1);
    if (bwave) { WAITVN(8); } else { WAITVN(4); }
    BARRIER();
    ldA4(0, 0, 0, A0); ldBn(0, 0, B0);

    for (int t = 0; t < NT; ++t) {
        const bool pref = (t + 2 < NT);
        ldA4(t, 0, 1, A1);
        mfmaQ<0, BNF>(acc, A0, B0);
        if (pref) { if (bwave) { WAITVN(4); } else { WAITVN(2); } }
        else      { WAITVN(0); }
        BARRIER();
        ldA4(t, 1, 0, A0); ldBn(t, 1, B1);
        if (pref) { stA(t + 2, 0); stB(t + 2, 0); }
        mfmaQ<1, BNF>(acc, A1, B0);
        BARRIER();
        ldA4(t, 1, 1, A1);
        mfmaQ<0, BNF>(acc, A0, B1);
        BARRIER();
        if (t + 1 < NT) { ldA4(t + 1, 0, 0, A0); ldBn(t + 1, 0, B0); }
        if (pref) { stA(t + 2, 1); stB(t + 2, 1); }
        mfmaQ<1, BNF>(acc, A1, B1);
        BARRIER();
    }

    const int colb = n0 + wc * (BNF * 16) + fr;
    const int rowb = m0 + (wr << 7) + fg * 4;
    #pragma unroll
    for (int rf = 0; rf < 8; ++rf)
        #pragma unroll
        for (int cf = 0; cf < BNF; ++cf) {
            const int col = colb + cf * 16;
            #pragma unroll
            for (int r = 0; r < 4; ++r) {
                const int row = rowb + rf * 16 + r;
                const float v = acc[rf][cf][r];
                if (Cf  && col >= flo  && col < fhi)  Cf [(size_t)row * ldf  + col - flo]  = v;
                if (Cb1 && col >= b1lo && col < b1hi) Cb1[(size_t)row * ldb1 + col - b1lo] = (bf16_t)v;
                if (Cb2 && col >= b2lo && col < b2hi) Cb2[(size_t)row * ldb2 + col - b2lo] = (bf16_t)v;
            }
        }
}

// ======  128x192 GEMM, counted-vmcnt loop, 80KB LDS -> 2 blocks/CU  ======
template<int RH>
__device__ __forceinline__ void mfmaH(f32x4 (&acc)[4][3], const bf16x8 (&af)[2],
                                      const bf16x8 (&bfv)[3]) {
    __builtin_amdgcn_s_setprio(1);
    #pragma unroll
    for (int i = 0; i < 2; ++i)
        #pragma unroll
        for (int cf = 0; cf < 3; ++cf)
            acc[RH*2+i][cf] = __builtin_amdgcn_mfma_f32_16x16x32_bf16(af[i], bfv[cf], acc[RH*2+i][cf], 0, 0, 0);
    __builtin_amdgcn_s_setprio(0);
}

__global__ __launch_bounds__(512, 4) void gemm128(
    const bf16_t* __restrict__ A, const bf16_t* __restrict__ B, int N, int K,
    float* __restrict__ Cf, int ldf,
    bf16_t* __restrict__ Cb1, int ldb1,
    bf16_t* __restrict__ vt, float cbscale)
{
    __shared__ char LDS[32768 + 49152];        // A-ring 4x8KB, B-ring 4x12KB
    char* Lc = LDS;
    const int tid = threadIdx.x;
    const int wv = tid >> 6, lane = tid & 63;
    const int fr = lane & 15, fg = lane >> 4;
    const int wr = wv >> 2, wc = wv & 3;
    const bool bwave = (wv < 6);

    int lin = blockIdx.y * gridDim.x + blockIdx.x;
    const int nwg = gridDim.x * gridDim.y;
    if ((nwg & 7) == 0) lin = (lin & 7) * (nwg >> 3) + (lin >> 3);
    const int bx = lin % gridDim.x, by = lin / gridDim.x;
    const int m0 = by << 7, n0 = bx * 192;

    const uint32_t slot4 = (uint32_t)((fg ^ ((fr >> 1) & 3)) << 4);

    const int ga = tid ^ ((tid >> 3) & 3);
    const bf16_t* agp = A + (size_t)(m0 + (ga >> 2)) * K + (ga & 3) * 8;
    const uint32_t aoff = (uint32_t)(wv * 1024);
    const bf16_t* bgp[2]; uint32_t boff[2];
    #pragma unroll
    for (int j = 0; j < 2; ++j) {
        const int cb = j * 384 + tid;
        const int gb = cb ^ ((cb >> 3) & 3);
        int br = n0 + (gb >> 2); if (br > N - 1) br = N - 1;
        bgp[j] = B + (size_t)br * K + (gb & 3) * 8;
        boff[j] = (uint32_t)(j * 6144 + wv * 1024);
    }

    f32x4 acc[4][3];
    f32x4 zero = {0.f, 0.f, 0.f, 0.f};
    #pragma unroll
    for (int i = 0; i < 4; ++i)
        #pragma unroll
        for (int j = 0; j < 3; ++j) acc[i][j] = zero;

    bf16x8 A0[2], A1[2], B0[3], B1[3];
    const int rowA = (wr << 6) + fr;
    const int rowB = wc * 48 + fr;

    auto stA = [&](int t, int kh) {
        const uint32_t sb = (uint32_t)(((2*t + kh) & 3) << 13);
        async_ld16(agp + t * 64 + kh * 32, Lc + sb + aoff);
    };
    auto stB = [&](int t, int kh) {
        const uint32_t sb = 32768u + (uint32_t)(((2*t + kh) & 3) * 12288);
        if (tid < 384) {
            #pragma unroll
            for (int j = 0; j < 2; ++j)
                async_ld16(bgp[j] + t * 64 + kh * 32, Lc + sb + boff[j]);
        }
    };
    auto ldA2 = [&](int t, int kh, int rh, bf16x8 (&dst)[2]) {
        const uint32_t base = (uint32_t)(((2*t + kh) & 3) << 13);
        #pragma unroll
        for (int i = 0; i < 2; ++i)
            dst[i] = *(const bf16x8*)(Lc + base + (rowA + (rh * 2 + i) * 16) * 64 + slot4);
    };
    auto ldB3 = [&](int t, int kh, bf16x8 (&dst)[3]) {
        const uint32_t base = 32768u + (uint32_t)(((2*t + kh) & 3) * 12288);
        #pragma unroll
        for (int cf = 0; cf < 3; ++cf)
            dst[cf] = *(const bf16x8*)(Lc + base + (rowB + cf * 16) * 64 + slot4);
    };

    const int NT = K >> 6;
    stA(0, 0); stB(0, 0); stA(0, 1); stB(0, 1);
    stA(1, 0); stB(1, 0); stA(1, 1); stB(1, 1);
    if (bwave) { WAITVN(6); } else { WAITVN(2); }
    BARRIER();
    ldA2(0, 0, 0, A0); ldB3(0, 0, B0);

    for (int t = 0; t < NT; ++t) {
        const bool pref = (t + 2 < NT);
        ldA2(t, 0, 1, A1);
        mfmaH<0>(acc, A0, B0);
        if (pref) { if (bwave) { WAITVN(3); } else { WAITVN(1); } }
        else      { WAITVN(0); }
        BARRIER();
        ldA2(t, 1, 0, A0); ldB3(t, 1, B1);
        if (pref) { stA(t + 2, 0); stB(t + 2, 0); }
        mfmaH<1>(acc, A1, B0);
        BARRIER();
        ldA2(t, 1, 1, A1);
        mfmaH<0>(acc, A0, B1);
        BARRIER();
        if (t + 1 < NT) { ldA2(t + 1, 0, 0, A0); ldB3(t + 1, 0, B0); }
        if (pref) { stA(t + 2, 1); stB(t + 2, 1); }
        mfmaH<1>(acc, A1, B1);
        BARRIER();
    }

    const int colb = n0 + wc * 48 + fr;
    const int rowb = m0 + (wr << 6) + fg * 4;
    if (vt) {
        #pragma unroll
        for (int rf = 0; rf < 4; ++rf) {
            const int row0 = rowb + rf * 16;
            const int bb = row0 >> 11, s0 = row0 & 2047;
            #pragma unroll
            for (int cf = 0; cf < 3; ++cf) {
                const int col = colb + cf * 16;
                const int h = col / 192;
                const int dm = col - h * 192;
                if (dm < 64) {
                    #pragma unroll
                    for (int r = 0; r < 4; ++r)
                        Cb1[(size_t)(row0 + r) * ldb1 + col] = (bf16_t)acc[rf][cf][r];
                } else {
                    bf16x4 o;
                    o[0] = (bf16_t)acc[rf][cf][0];
                    o[1] = (bf16_t)acc[rf][cf][1];
                    o[2] = (bf16_t)acc[rf][cf][2];
                    o[3] = (bf16_t)acc[rf][cf][3];
                    *(bf16x4*)(vt + ((size_t)((bb * 24 + h) * 128 + dm - 64)) * 2048 + s0) = o;
                }
            }
        }
    } else {
        #pragma unroll
        for (int rf = 0; rf < 4; ++rf)
            #pragma unroll
            for (int cf = 0; cf < 3; ++cf) {
                const int col = colb + cf * 16;
                #pragma unroll
                for (int r = 0; r < 4; ++r) {
                    const int row = rowb + rf * 16 + r;
                    const float v = acc[rf][cf][r];
                    if (Cf)  Cf [(size_t)row * ldf  + col] = v;
                    if (Cb1) Cb1[(size_t)row * ldb1 + col] = (bf16_t)(v * cbscale);
                }
            }
    }
}

// =========================  RoPE tables (fp32)  =========================
__global__ void rope_tab(float* __restrict__ ctab, float* __restrict__ stab)
{
    const int idx = blockIdx.x * 256 + threadIdx.x;
    if (idx >= S_LEN * 32) return;
    const int s = idx >> 5, i = idx & 31;
    const float freq = powf(10000.0f, -(float)(2 * i) * (1.0f / 128.0f));
    const float ang = (float)s * freq;
    ctab[idx] = cosf(ang);
    stab[idx] = sinf(ang);
}

// ====  unified RoPE: Q (vectorized bf16x8, in-place) + shared K-rope  ====
__global__ __launch_bounds__(256) void rope_all(
    bf16_t* __restrict__ q, const float* __restrict__ kvd, bf16_t* __restrict__ kr,
    const float* __restrict__ ctab, const float* __restrict__ stab)
{
    const int idx = blockIdx.x * 256 + threadIdx.x;
    if (idx < NTOK * N_HEADS * 4) {
        const int c = idx & 3;
        const int rest = idx >> 2;
        const int h = rest % N_HEADS;
        const int tok = rest / N_HEADS;
        const int s = tok & (S_LEN - 1);
        bf16_t* p = q + (size_t)tok * D_MODEL + h * HEAD_DIM + 64 + c * 8;
        bf16x8 a = *(const bf16x8*)(p);
        bf16x8 b = *(const bf16x8*)(p + 32);
        const float4* cp = (const float4*)(ctab + s * 32 + c * 8);
        const float4* sp = (const float4*)(stab + s * 32 + c * 8);
        float4 c0 = cp[0], c1 = cp[1];
        float4 s0 = sp[0], s1 = sp[1];
        float cs[8] = {c0.x, c0.y, c0.z, c0.w, c1.x, c1.y, c1.z, c1.w};
        float sn[8] = {s0.x, s0.y, s0.z, s0.w, s1.x, s1.y, s1.z, s1.w};
        bf16x8 oa, ob;
        #pragma unroll
        for (int j = 0; j < 8; ++j) {
            const float av = (float)a[j], bv = (float)b[j];
            oa[j] = (bf16_t)(av * cs[j] - bv * sn[j]);
            ob[j] = (bf16_t)(bv * cs[j] + av * sn[j]);
        }
        *(bf16x8*)(p)      = oa;
        *(bf16x8*)(p + 32) = ob;
    } else {
        const int kx = idx - NTOK * N_HEADS * 4;
        if (kx >= NTOK * 32) return;
        const int i = kx & 31;
        const int tok = kx >> 5;
        const int s = tok & (S_LEN - 1);
        const float* p = kvd + (size_t)tok * KVDN + KV_PROJ;
        const float a = p[i], b = p[i + 32];
        const float c = ctab[s * 32 + i], sn = stab[s * 32 + i];
        kr[(size_t)tok * 64 + i]      = (bf16_t)(a * c - b * sn);
        kr[(size_t)tok * 64 + i + 32] = (bf16_t)(b * c + a * sn);
    }
}

// ======  causal flash attention (R8: K/Krp/V LDS dbuf, paired q-tiles,
// swapped QK, reg-P, defer-max). Q pre-scaled by (1/sqrt(128))*log2(e).
__global__ __launch_bounds__(256, 2) void attn_fwd(
    const bf16_t* __restrict__ Q, const bf16_t* __restrict__ KVUP,
    const bf16_t* __restrict__ KR, const bf16_t* __restrict__ VT,
    bf16_t* __restrict__ AO)
{
    __shared__ bf16_t Knr[2][64 * 64];
    __shared__ bf16_t Krp[2][64 * 64];
    __shared__ bf16_t Vls[2][128 * 64];

    const int bh = blockIdx.y;
    const int b = bh / N_HEADS, h = bh % N_HEADS;
    const int wave = threadIdx.x >> 6, lane = threadIdx.x & 63;
    const int fr = lane & 15, fg = lane >> 4;
    const int rx = fr & 7;
    const int hi = fg >> 1;
    const int s0l = fr + 32 * (fg & 1);
    const int s1l = s0l + 16;

    const bf16_t* Kb  = KVUP + (size_t)b * S_LEN * KVUN + (size_t)h * 192;
    const bf16_t* KRb = KR + (size_t)b * S_LEN * 64;
    const bf16_t* Vb  = VT + (size_t)bh * HEAD_DIM * S_LEN;

    const int srow   = lane >> 3;
    const int schunk = (lane & 7) ^ srow;

    f32x4 zero = {0.f, 0.f, 0.f, 0.f};

    #pragma unroll 1
    for (int tp = 0; tp < 2; ++tp) {
        const int qt = (tp == 0) ? blockIdx.x : (15 - blockIdx.x);
        const int qb = qt * 128;
        const int wrow0 = qb + wave * 32;

        bf16x8 qf[2][4];
        #pragma unroll
        for (int rf = 0; rf < 2; ++rf)
            #pragma unroll
            for (int kc = 0; kc < 4; ++kc)
                qf[rf][kc] = *(const bf16x8*)(Q + (size_t)(b * S_LEN + wrow0 + rf * 16 + fr) * D_MODEL
                                              + h * HEAD_DIM + kc * 32 + fg * 8);
        f32x4 oacc[2][8];
        float m_i[2], l_i[2];
        #pragma unroll
        for (int rf = 0; rf < 2; ++rf) {
            #pragma unroll
            for (int nf = 0; nf < 8; ++nf) oacc[rf][nf] = zero;
            m_i[rf] = -1e30f; l_i[rf] = 0.f;
        }

        auto stage = [&](int kvb, int bf) {
            #pragma unroll
            for (int c = 0; c < 2; ++c) {
                const int r0 = wave * 16 + c * 8;
                async_ld16(Kb  + (size_t)(kvb + r0 + srow) * KVUN + schunk * 8, &Knr[bf][r0 * 64]);
                async_ld16(KRb + (size_t)(kvb + r0 + srow) * 64   + schunk * 8, &Krp[bf][r0 * 64]);
            }
            #pragma unroll
            for (int c = 0; c < 4; ++c) {
                const int r0 = wave * 32 + c * 8;
                async_ld16(Vb + (size_t)(r0 + srow) * S_LEN + kvb + schunk * 8, &Vls[bf][r0 * 64]);
            }
        };

        const int kvend = qb + 128;
        int cur = 0;
        stage(0, 0);
        __syncthreads();

        #pragma unroll 1
        for (int kvb = 0; kvb < kvend; kvb += 64) {
            if (kvb + 64 < kvend) stage(kvb + 64, cur ^ 1);

            if (kvb <= wrow0 + 31) {
                const bf16_t* Kc = Knr[cur];
                const bf16_t* Rc = Krp[cur];
                const bf16_t* Vc = Vls[cur];

                f32x4 sacc[2][4];
                #pragma unroll
                for (int rf = 0; rf < 2; ++rf)
                    #pragma unroll
                    for (int jn = 0; jn < 4; ++jn) sacc[rf][jn] = zero;
                __builtin_amdgcn_s_setprio(1);
                #pragma unroll
                for (int jn = 0; jn < 4; ++jn) {
                    const int krow = jn * 16 + fr;
                    bf16x8 kA = *(const bf16x8*)(Kc + krow * 64 + (((0 + fg) ^ rx) << 3));
                    bf16x8 kB = *(const bf16x8*)(Kc + krow * 64 + (((4 + fg) ^ rx) << 3));
                    bf16x8 kC = *(const bf16x8*)(Rc + krow * 64 + (((0 + fg) ^ rx) << 3));
                    bf16x8 kD = *(const bf16x8*)(Rc + krow * 64 + (((4 + fg) ^ rx) << 3));
                    #pragma unroll
                    for (int rf = 0; rf < 2; ++rf) {
                        sacc[rf][jn] = __builtin_amdgcn_mfma_f32_16x16x32_bf16(kA, qf[rf][0], sacc[rf][jn], 0, 0, 0);
                        sacc[rf][jn] = __builtin_amdgcn_mfma_f32_16x16x32_bf16(kB, qf[rf][1], sacc[rf][jn], 0, 0, 0);
                        sacc[rf][jn] = __builtin_amdgcn_mfma_f32_16x16x32_bf16(kC, qf[rf][2], sacc[rf][jn], 0, 0, 0);
                        sacc[rf][jn] = __builtin_amdgcn_mfma_f32_16x16x32_bf16(kD, qf[rf][3], sacc[rf][jn], 0, 0, 0);
                    }
                }
                __builtin_amdgcn_s_setprio(0);

                const bool needMask = (kvb + 63 > wrow0);
                uint32_t pk[2][4][2];
                #pragma unroll
                for (int rf = 0; rf < 2; ++rf) {
                    const int qrow = wrow0 + rf * 16 + fr;
                    float mx = -1e30f;
                    #pragma unroll
                    for (int jn = 0; jn < 4; ++jn)
                        #pragma unroll
                        for (int r = 0; r < 4; ++r) {
                            float v = sacc[rf][jn][r];
                            if (needMask && (kvb + jn * 16 + fg * 4 + r > qrow)) v = -1e30f;
                            sacc[rf][jn][r] = v;
                            mx = fmaxf(mx, v);
                        }
                    mx = fmaxf(mx, __shfl_xor(mx, 16));
                    mx = fmaxf(mx, __shfl_xor(mx, 32));
                    if (!__all(mx <= m_i[rf] + 8.f)) {
                        const float mn = fmaxf(m_i[rf], mx);
                        const float sc = __builtin_amdgcn_exp2f(m_i[rf] - mn);
                        m_i[rf] = mn;
                        l_i[rf] *= sc;
                        #pragma unroll
                        for (int nf = 0; nf < 8; ++nf)
                            #pragma unroll
                            for (int r = 0; r < 4; ++r) oacc[rf][nf][r] *= sc;
                    }
                    const float mn = m_i[rf];
                    float ls = 0.f;
                    #pragma unroll
                    for (int jn = 0; jn < 4; ++jn) {
                        float p0 = __builtin_amdgcn_exp2f(sacc[rf][jn][0] - mn);
                        float p1 = __builtin_amdgcn_exp2f(sacc[rf][jn][1] - mn);
                        float p2 = __builtin_amdgcn_exp2f(sacc[rf][jn][2] - mn);
                        float p3 = __builtin_amdgcn_exp2f(sacc[rf][jn][3] - mn);
                        ls += (p0 + p1) + (p2 + p3);
                        union { bf16x4 h; uint32_t w[2]; } cv;
                        cv.h[0] = (bf16_t)p0; cv.h[1] = (bf16_t)p1;
                        cv.h[2] = (bf16_t)p2; cv.h[3] = (bf16_t)p3;
                        pk[rf][jn][0] = cv.w[0]; pk[rf][jn][1] = cv.w[1];
                    }
                    ls += __shfl_xor(ls, 16);
                    ls += __shfl_xor(ls, 32);
                    l_i[rf] += ls;
                }

                bf16x8 bfr[2][2];
                #pragma unroll
                for (int rf = 0; rf < 2; ++rf)
                    #pragma unroll
                    for (int ks = 0; ks < 2; ++ks) {
                        const uint32_t t00 = __shfl(pk[rf][2*ks][0],   s0l);
                        const uint32_t t01 = __shfl(pk[rf][2*ks][1],   s0l);
                        const uint32_t t10 = __shfl(pk[rf][2*ks+1][0], s0l);
                        const uint32_t t11 = __shfl(pk[rf][2*ks+1][1], s0l);
                        const uint32_t u00 = __shfl(pk[rf][2*ks][0],   s1l);
                        const uint32_t u01 = __shfl(pk[rf][2*ks][1],   s1l);
                        const uint32_t u10 = __shfl(pk[rf][2*ks+1][0], s1l);
                        const uint32_t u11 = __shfl(pk[rf][2*ks+1][1], s1l);
                        union { bf16x8 h; uint32_t w[4]; } bb;
                        bb.w[0] = hi ? t10 : t00;
                        bb.w[1] = hi ? t11 : t01;
                        bb.w[2] = hi ? u10 : u00;
                        bb.w[3] = hi ? u11 : u01;
                        bfr[rf][ks] = bb.h;
                    }

                __builtin_amdgcn_s_setprio(1);
                #pragma unroll
                for (int nf = 0; nf < 8; ++nf) {
                    const int vrow = nf * 16 + fr;
                    bf16x8 v0 = *(const bf16x8*)(Vc + vrow * 64 + (((0 + fg) ^ rx) << 3));
                    bf16x8 v1 = *(const bf16x8*)(Vc + vrow * 64 + (((4 + fg) ^ rx) << 3));
                    #pragma unroll
                    for (int rf = 0; rf < 2; ++rf) {
                        oacc[rf][nf] = __builtin_amdgcn_mfma_f32_16x16x32_bf16(v0, bfr[rf][0], oacc[rf][nf], 0, 0, 0);
                        oacc[rf][nf] = __builtin_amdgcn_mfma_f32_16x16x32_bf16(v1, bfr[rf][1], oacc[rf][nf], 0, 0, 0);
                    }
                }
                __builtin_amdgcn_s_setprio(0);
            }
            __syncthreads();
            cur ^= 1;
        }

        #pragma unroll
        for (int rf = 0; rf < 2; ++rf) {
            const float rl = __builtin_amdgcn_rcpf(l_i[rf]);
            const int qrow = wrow0 + rf * 16 + fr;
            bf16_t* aob = AO + (size_t)(b * S_LEN + qrow) * D_MODEL + h * HEAD_DIM + fg * 4;
            #pragma unroll
            for (int nf = 0; nf < 8; ++nf) {
                bf16x4 o;
                o[0] = (bf16_t)(oacc[rf][nf][0] * rl);
                o[1] = (bf16_t)(oacc[rf][nf][1] * rl);
                o[2] = (bf16_t)(oacc[rf][nf][2] * rl);
                o[3] = (bf16_t)(oacc[rf][nf][3] * rl);
                *(bf16x4*)(aob + nf * 16) = o;
            }
        }
    }
}

// ============================  launch  ============================
extern "C" void kernel_launch(void* const* d_in, const int* in_sizes, int n_in,
                              void* d_out, int out_size, void* d_ws, size_t ws_size,
                              hipStream_t stream)
{
    const float* x     = (const float*)d_in[0];
    const float* scale = (const float*)d_in[1];
    const float* w_dq  = (const float*)d_in[2];
    const float* w_uq  = (const float*)d_in[3];
    const float* w_dkv = (const float*)d_in[4];
    const float* w_ukv = (const float*)d_in[5];
    const float* w_o   = (const float*)d_in[6];
    float* out0 = (float*)d_out;                        // (4096, 3072)
    float* out1 = out0 + (size_t)NTOK * D_MODEL;        // (4096, 2112)

    if (ws_size < 187039744ull) return;
    char* ws = (char*)d_ws;
    bf16_t* XN    = (bf16_t*)(ws + 0);
    bf16_t* WCAT  = (bf16_t*)(ws + 25165824ull);        // [3648][3072] b^T (dq|dkv)
    bf16_t* WUQT  = (bf16_t*)(ws + 47579136ull);
    bf16_t* WUKVT = (bf16_t*)(ws + 57016320ull);
    bf16_t* WOB   = (bf16_t*)(ws + 75890688ull);
    bf16_t* QD    = (bf16_t*)(ws + 94765056ull);
    bf16_t* Qb    = (bf16_t*)(ws + 107347968ull);
    bf16_t* KVNR  = (bf16_t*)(ws + 132513792ull);
    bf16_t* KVUP  = (bf16_t*)(ws + 149291008ull);
    bf16_t* KRB   = (bf16_t*)(ws + 94765056ull);        // aliases QD (after q_up)
    float*  CTAB  = (float*) (ws + 95289344ull);        // in QD region (after q_up)
    float*  STAB  = (float*) (ws + 95551488ull);
    bf16_t* VTb   = WCAT;                               // reuses WCAT (after down-proj)
    bf16_t* AO    = XN;

    const float l2e_isc = 0.127500625f;                 // (1/sqrt(128)) * log2(e)

    // fused pre-pass: RMSNorm (4096 blocks) + weight prep (33984 blocks)
    fused_pre<<<NTOK + 33984, 256, 0, stream>>>(x, scale, XN,
        w_dq, w_uq, w_dkv, w_ukv, w_o, WCAT, WUQT, WUKVT, WOB);

    // fused down-proj: N=3648, BN=256, grid 240 (1 gen) — R14 proven config
    gemm256<4><<<dim3(15, 16), 512, 0, stream>>>(XN, WCAT, 3648, 3072,
        out1, KVDN, 1536, 3648,
        QD,   Q_PROJ, 0, 1536,
        KVNR, KV_PROJ, 1536, 3584);
    // q_up: 128x192 tiles, grid 16x32 = 512 blocks (2/CU); prescaled output
    gemm128<<<dim3(16, 32), 512, 0, stream>>>(QD, WUQT, 3072, 1536,
        nullptr, 0, Qb, D_MODEL, nullptr, l2e_isc);
    rope_tab<<<(S_LEN * 32 + 255) / 256, 256, 0, stream>>>(CTAB, STAB);
    rope_all<<<2048, 256, 0, stream>>>(Qb, out1, KRB, CTAB, STAB);
    // kv_up: 128x192 tiles, grid 24x32 = 768 blocks; fused V-transpose epilogue
    gemm128<<<dim3(24, 32), 512, 0, stream>>>(KVNR, WUKVT, 4608, 2048,
        nullptr, 0, KVUP, KVUN, VTb, 1.0f);
    // paired attn (R8): grid 8x48
    attn_fwd<<<dim3(8, 48), 256, 0, stream>>>(Qb, KVUP, KRB, VTb, AO);
    // output projection: 128x192 tiles, grid 16x32
    gemm128<<<dim3(16, 32), 512, 0, stream>>>(AO, WOB, 3072, 3072,
        out0, D_MODEL, nullptr, 0, nullptr, 1.0f);
}